// Round 1
// baseline (677.814 us; speedup 1.0000x reference)
//
#include <hip/hip_runtime.h>
#include <stdint.h>

#define HW 3600
#define NBATCH 2
#define CDIM 256
#define KNN 64
#define M_REAL 7200
#define PADM 7232          // 7200 padded to multiple of 64 (113*64)

// ---------------------------------------------------------------------------
// Top-K (64 nearest, incl. self) per query point.
// One block per query. d2 row staged in LDS; per-thread strip-min in register;
// 64 rounds of wave-shuffle argmin; only the winning element's owner rescans.
// Key = (f32bits(d2) << 32) | j  -> min gives (smallest d2, smallest index),
// matching jax.lax.top_k tie-breaking. sqrt omitted (monotone).
// ---------------------------------------------------------------------------
__global__ __launch_bounds__(256) void topk_kernel(const float* __restrict__ points,
                                                   int* __restrict__ idx_out) {
    const int q = blockIdx.x;            // 0..7199
    const int n = q / HW;
    const int i = q - n * HW;
    const int t = threadIdx.x;

    __shared__ float d2s[HW];
    __shared__ unsigned long long wmin[4];
    __shared__ int win[KNN];

    const float* __restrict__ px = points + (size_t)n * 3 * HW;
    const float* __restrict__ py = px + HW;
    const float* __restrict__ pz = py + HW;

    const float xi = px[i], yi = py[i], zi = pz[i];
    const float sqi = xi * xi + yi * yi + zi * zi;

    unsigned long long lkey = ~0ULL;
    #pragma unroll
    for (int s = 0; s < 15; ++s) {
        int j = t + (s << 8);
        if (j < HW) {
            float xj = px[j], yj = py[j], zj = pz[j];
            float sqj = xj * xj + yj * yj + zj * zj;
            float d2 = sqi + sqj - 2.0f * (xi * xj + yi * yj + zi * zj);
            d2 = fmaxf(d2, 0.0f);
            d2s[j] = d2;
            unsigned long long key =
                ((unsigned long long)__float_as_uint(d2) << 32) | (unsigned int)j;
            if (key < lkey) lkey = key;
        }
    }
    __syncthreads();

    const int wave = t >> 6;
    for (int r = 0; r < KNN; ++r) {
        unsigned long long k = lkey;
        #pragma unroll
        for (int off = 1; off < 64; off <<= 1) {
            unsigned long long o = __shfl_xor(k, off, 64);
            if (o < k) k = o;
        }
        if ((t & 63) == 0) wmin[wave] = k;
        __syncthreads();
        unsigned long long w01 = wmin[0] < wmin[1] ? wmin[0] : wmin[1];
        unsigned long long w23 = wmin[2] < wmin[3] ? wmin[2] : wmin[3];
        unsigned long long w = w01 < w23 ? w01 : w23;
        int jw = (int)(w & 0xFFFFFFFFULL);
        if (t == 0) win[r] = jw;
        if ((jw & 255) == t) {
            d2s[jw] = __uint_as_float(0x7F800000u);  // +inf: remove winner
            unsigned long long nk = ~0ULL;
            #pragma unroll
            for (int s = 0; s < 15; ++s) {
                int j = t + (s << 8);
                if (j < HW) {
                    unsigned long long key =
                        ((unsigned long long)__float_as_uint(d2s[j]) << 32) | (unsigned int)j;
                    if (key < nk) nk = key;
                }
            }
            lkey = nk;
        }
        __syncthreads();
    }
    if (t < KNN) idx_out[(size_t)q * KNN + t] = win[t];
}

// ---------------------------------------------------------------------------
// h0 init: NH[(n*HW+hw)*512 + c] = cnn[n][c][hw]   (left half of NH rows)
// ---------------------------------------------------------------------------
__global__ __launch_bounds__(256) void init_h(const float* __restrict__ cnn,
                                              float* __restrict__ NH) {
    __shared__ float tile[32][33];
    const int hw0 = blockIdx.x * 32;
    const int c0 = blockIdx.y * 32;
    const int n = blockIdx.z;
    const int tx = threadIdx.x & 31;
    const int ty = threadIdx.x >> 5;   // 0..7
    const float* __restrict__ src = cnn + (size_t)n * CDIM * HW;
    #pragma unroll
    for (int r = 0; r < 4; ++r) {
        int cc = ty + r * 8;
        int hw = hw0 + tx;
        if (hw < HW) tile[cc][tx] = src[(size_t)(c0 + cc) * HW + hw];
    }
    __syncthreads();
    #pragma unroll
    for (int r = 0; r < 4; ++r) {
        int hh = ty + r * 8;
        int hw = hw0 + hh;
        if (hw < HW) NH[(size_t)(n * HW + hw) * 512 + c0 + tx] = tile[tx][hh];
    }
}

// zero the 32 padded rows (512 cols) of both NH buffers
__global__ __launch_bounds__(256) void zero_pads(float* __restrict__ NHa,
                                                 float* __restrict__ NHb) {
    int t = blockIdx.x * 256 + threadIdx.x;
    if (t < 32 * 512) {
        NHa[(size_t)M_REAL * 512 + t] = 0.0f;
        NHb[(size_t)M_REAL * 512 + t] = 0.0f;
    }
}

// ---------------------------------------------------------------------------
// C[m][n] = relu( sum_k A[m][k] * W[n][k] + bias[n] )
// A row-major (lda), W row-major (ldw = K). Tiles 64x64xBK32, 4x4 per thread.
// M is padded (PADM) so no row guards needed.
// ---------------------------------------------------------------------------
#define BM 64
#define BN 64
#define BK 32
__global__ __launch_bounds__(256) void gemm_bias_relu(
    const float* __restrict__ A, int lda,
    const float* __restrict__ W, int ldw,
    const float* __restrict__ bias,
    float* __restrict__ Co, int ldc,
    int Kk) {
    __shared__ float As[BK][BM];
    __shared__ float Bs[BK][BN];
    const int m0 = blockIdx.x * BM;
    const int n0 = blockIdx.y * BN;
    const int tid = threadIdx.x;
    const int lr = tid >> 3;            // 0..31
    const int lk = (tid & 7) << 2;      // 0,4,...,28
    const int tx = tid & 15;            // 0..15 (cols)
    const int ty = tid >> 4;            // 0..15 (rows)

    float acc[4][4];
    #pragma unroll
    for (int a = 0; a < 4; ++a)
        #pragma unroll
        for (int b = 0; b < 4; ++b) acc[a][b] = 0.0f;

    for (int k0 = 0; k0 < Kk; k0 += BK) {
        #pragma unroll
        for (int h = 0; h < 2; ++h) {
            int row = lr + h * 32;
            float4 av = *(const float4*)&A[(size_t)(m0 + row) * lda + k0 + lk];
            As[lk + 0][row] = av.x; As[lk + 1][row] = av.y;
            As[lk + 2][row] = av.z; As[lk + 3][row] = av.w;
            float4 bv = *(const float4*)&W[(size_t)(n0 + row) * ldw + k0 + lk];
            Bs[lk + 0][row] = bv.x; Bs[lk + 1][row] = bv.y;
            Bs[lk + 2][row] = bv.z; Bs[lk + 3][row] = bv.w;
        }
        __syncthreads();
        #pragma unroll
        for (int k = 0; k < BK; ++k) {
            float4 a4 = *(const float4*)&As[k][ty * 4];
            float4 b4 = *(const float4*)&Bs[k][tx * 4];
            float av[4] = {a4.x, a4.y, a4.z, a4.w};
            float bv[4] = {b4.x, b4.y, b4.z, b4.w};
            #pragma unroll
            for (int ii = 0; ii < 4; ++ii)
                #pragma unroll
                for (int jj = 0; jj < 4; ++jj)
                    acc[ii][jj] = fmaf(av[ii], bv[jj], acc[ii][jj]);
        }
        __syncthreads();
    }

    float4 bb = *(const float4*)&bias[n0 + tx * 4];
    const float b0 = bb.x, b1 = bb.y, b2 = bb.z, b3 = bb.w;
    #pragma unroll
    for (int ii = 0; ii < 4; ++ii) {
        int row = m0 + ty * 4 + ii;
        float4 o;
        o.x = fmaxf(acc[ii][0] + b0, 0.0f);
        o.y = fmaxf(acc[ii][1] + b1, 0.0f);
        o.z = fmaxf(acc[ii][2] + b2, 0.0f);
        o.w = fmaxf(acc[ii][3] + b3, 0.0f);
        *(float4*)&Co[(size_t)row * ldc + n0 + tx * 4] = o;
    }
}

// ---------------------------------------------------------------------------
// message[q][c] = (1/64) * sum_k T[n*HW + idx[q][k]][c]  -> NH right half
// ---------------------------------------------------------------------------
__global__ __launch_bounds__(256) void gather_mean(const float* __restrict__ T,
                                                   const int* __restrict__ idx,
                                                   float* __restrict__ NH) {
    const int q = blockIdx.x;
    const int n = q / HW;
    const int t = threadIdx.x;
    __shared__ int nbr[KNN];
    if (t < KNN) nbr[t] = idx[(size_t)q * KNN + t];
    __syncthreads();
    float sum = 0.0f;
    #pragma unroll 8
    for (int k = 0; k < KNN; ++k) {
        int r = n * HW + nbr[k];
        sum += T[(size_t)r * CDIM + t];
    }
    NH[(size_t)q * 512 + CDIM + t] = sum * (1.0f / KNN);
}

// out[n][0:256][hw] = cnn_feature
__global__ __launch_bounds__(256) void copy_cnn(const float* __restrict__ cnn,
                                                float* __restrict__ out) {
    int f = blockIdx.x * 256 + threadIdx.x;
    const int per = CDIM * HW;
    if (f < NBATCH * per) {
        int n = f / per;
        int rem = f - n * per;
        out[(size_t)n * (2 * CDIM * HW) + rem] = cnn[f];
    }
}

// out[n][256 + c][hw] = Hf[(n*HW+hw)*512 + c]
__global__ __launch_bounds__(256) void final_out(const float* __restrict__ Hf,
                                                 float* __restrict__ out) {
    __shared__ float tile[32][33];
    const int hw0 = blockIdx.x * 32;
    const int c0 = blockIdx.y * 32;
    const int n = blockIdx.z;
    const int tx = threadIdx.x & 31;
    const int ty = threadIdx.x >> 5;
    #pragma unroll
    for (int r = 0; r < 4; ++r) {
        int hh = ty + r * 8;
        int hw = hw0 + hh;
        if (hw < HW) tile[hh][tx] = Hf[(size_t)(n * HW + hw) * 512 + c0 + tx];
    }
    __syncthreads();
    #pragma unroll
    for (int r = 0; r < 4; ++r) {
        int cc = ty + r * 8;
        int hw = hw0 + tx;
        if (hw < HW)
            out[(size_t)n * (2 * CDIM * HW) + (size_t)(CDIM + c0 + cc) * HW + hw] =
                tile[tx][cc];
    }
}

extern "C" void kernel_launch(void* const* d_in, const int* in_sizes, int n_in,
                              void* d_out, int out_size, void* d_ws, size_t ws_size,
                              hipStream_t stream) {
    const float* cnn   = (const float*)d_in[0];
    const float* pts   = (const float*)d_in[1];
    const float* mlp_w = (const float*)d_in[2];
    const float* mlp_b = (const float*)d_in[3];
    const float* rnn_w = (const float*)d_in[4];
    const float* rnn_b = (const float*)d_in[5];
    float* out = (float*)d_out;

    // workspace layout (fp32): NHa(7232x512) | NHb(7232x512) | T(7232x256) | idx(7200x64 int)
    float* NHa = (float*)d_ws;
    float* NHb = NHa + (size_t)PADM * 512;
    float* T   = NHb + (size_t)PADM * 512;
    int*   idx = (int*)(T + (size_t)PADM * CDIM);

    topk_kernel<<<M_REAL, 256, 0, stream>>>(pts, idx);
    init_h<<<dim3(113, 8, NBATCH), 256, 0, stream>>>(cnn, NHa);
    zero_pads<<<64, 256, 0, stream>>>(NHa, NHb);

    float* cur = NHa;
    float* nxt = NHb;
    for (int it = 0; it < 3; ++it) {
        // t = relu(mlp_w @ h + mlp_b): A = cur left half (lda=512), K=256
        gemm_bias_relu<<<dim3(PADM / BM, CDIM / BN), 256, 0, stream>>>(
            cur, 512, mlp_w, CDIM, mlp_b, T, CDIM, CDIM);
        // message = mean_k t[idx] -> cur right half
        gather_mean<<<M_REAL, 256, 0, stream>>>(T, idx, cur);
        // h' = relu(rnn_w @ [h;msg] + rnn_b): A = cur full row (K=512) -> nxt left half
        gemm_bias_relu<<<dim3(PADM / BM, CDIM / BN), 256, 0, stream>>>(
            cur, 512, rnn_w, 512, rnn_b, nxt, 512, 512);
        float* tmp = cur; cur = nxt; nxt = tmp;
    }

    copy_cnn<<<(NBATCH * CDIM * HW + 255) / 256, 256, 0, stream>>>(cnn, out);
    final_out<<<dim3(113, 8, NBATCH), 256, 0, stream>>>(cur, out);
}

// Round 2
// 430.492 us; speedup vs baseline: 1.5745x; 1.5745x over previous
//
#include <hip/hip_runtime.h>
#include <stdint.h>

#define HW 3600
#define NBATCH 2
#define CDIM 256
#define KNN 64
#define M_REAL 7200
#define PADM 7232          // 7200 padded to multiple of 64 (113*64)

// ---------------------------------------------------------------------------
// Top-K (64 nearest, incl. self) per query point — radix select.
// One block per query. d2 bit-patterns (monotone for >=0 floats) in LDS.
// 4 passes of 8-bit radix histogram + wave-scan find the exact 64th-smallest
// key T and the count of ties needed. Collection pass emits all keys < T
// (order-free: downstream is a mean). Ties at T resolved smallest-index-first
// (matches jax.lax.top_k); typically exactly 1 round.
// ---------------------------------------------------------------------------
__global__ __launch_bounds__(256) void topk_kernel(const float* __restrict__ points,
                                                   int* __restrict__ idx_out) {
    const int q = blockIdx.x;            // 0..7199
    const int n = q / HW;
    const int i = q - n * HW;
    const int t = threadIdx.x;

    __shared__ uint32_t keys[HW];        // 14400 B
    __shared__ uint32_t hist[256];
    __shared__ uint32_t wsum[4];
    __shared__ uint32_t s_prefix, s_want, s_cnt;
    __shared__ uint32_t wmin2[4];

    const float* __restrict__ px = points + (size_t)n * 3 * HW;
    const float* __restrict__ py = px + HW;
    const float* __restrict__ pz = py + HW;

    const float xi = px[i], yi = py[i], zi = pz[i];
    const float sqi = xi * xi + yi * yi + zi * zi;

    if (t == 0) { s_cnt = 0; }
    #pragma unroll
    for (int s = 0; s < 15; ++s) {
        int j = t + (s << 8);
        if (j < HW) {
            float xj = px[j], yj = py[j], zj = pz[j];
            float d2 = fmaxf(sqi + (xj * xj + yj * yj + zj * zj)
                             - 2.0f * (xi * xj + yi * yj + zi * zj), 0.0f);
            keys[j] = __float_as_uint(d2);
        }
    }
    hist[t] = 0;
    __syncthreads();

    uint32_t prefix = 0;
    uint32_t want = KNN;
    const int wave = t >> 6;

    #pragma unroll
    for (int shift = 24; shift >= 0; shift -= 8) {
        const uint32_t mask_hi = (shift == 24) ? 0u : (0xFFFFFFFFu << (shift + 8));
        // histogram of current byte among elements matching the fixed prefix
        #pragma unroll
        for (int s = 0; s < 15; ++s) {
            int j = t + (s << 8);
            if (j < HW) {
                uint32_t k = keys[j];
                if ((k & mask_hi) == prefix)
                    atomicAdd(&hist[(k >> shift) & 255], 1u);
            }
        }
        __syncthreads();
        const uint32_t myc = hist[t];
        // inclusive scan: wave-level shfl_up, then cross-wave via wsum
        uint32_t v = myc;
        #pragma unroll
        for (int off = 1; off < 64; off <<= 1) {
            uint32_t o = __shfl_up(v, off, 64);
            if ((t & 63) >= off) v += o;
        }
        if ((t & 63) == 63) wsum[wave] = v;
        __syncthreads();
        uint32_t add = 0;
        for (int w = 0; w < wave; ++w) add += wsum[w];
        v += add;                        // cumulative count over bins 0..t
        if (v >= want && (v - myc) < want) {   // exactly one thread: the threshold bin
            s_prefix = prefix | ((uint32_t)t << shift);
            s_want = want - (v - myc);
        }
        __syncthreads();
        hist[t] = 0;                     // clear for next pass
        prefix = s_prefix;
        want = s_want;
        __syncthreads();
    }

    const uint32_t T = prefix;           // exact 64th-smallest key value
    // collect all strictly-smaller keys (order irrelevant)
    #pragma unroll
    for (int s = 0; s < 15; ++s) {
        int j = t + (s << 8);
        if (j < HW) {
            uint32_t k = keys[j];
            if (k < T) {
                uint32_t pos = atomicAdd(&s_cnt, 1u);
                idx_out[(size_t)q * KNN + pos] = j;
            }
        }
    }
    // fill remaining `want` slots from ties at T, smallest indices first
    const int base = KNN - (int)want;
    for (int r = 0; r < (int)want; ++r) {
        uint32_t mi = 0xFFFFFFFFu;
        #pragma unroll
        for (int s = 0; s < 15; ++s) {
            int j = t + (s << 8);
            if (j < HW && keys[j] == T) mi = mi < (uint32_t)j ? mi : (uint32_t)j;
        }
        #pragma unroll
        for (int off = 1; off < 64; off <<= 1) {
            uint32_t o = __shfl_xor(mi, off, 64);
            mi = mi < o ? mi : o;
        }
        if ((t & 63) == 0) wmin2[wave] = mi;
        __syncthreads();
        uint32_t m01 = wmin2[0] < wmin2[1] ? wmin2[0] : wmin2[1];
        uint32_t m23 = wmin2[2] < wmin2[3] ? wmin2[2] : wmin2[3];
        uint32_t jw = m01 < m23 ? m01 : m23;
        if (t == 0) idx_out[(size_t)q * KNN + base + r] = (int)jw;
        if ((jw & 255) == (uint32_t)t) keys[jw] = 0xFFFFFFFFu;  // remove winner
        __syncthreads();
    }
}

// ---------------------------------------------------------------------------
// h0 init: NH[(n*HW+hw)*512 + c] = cnn[n][c][hw]   (left half of NH rows)
// ---------------------------------------------------------------------------
__global__ __launch_bounds__(256) void init_h(const float* __restrict__ cnn,
                                              float* __restrict__ NH) {
    __shared__ float tile[32][33];
    const int hw0 = blockIdx.x * 32;
    const int c0 = blockIdx.y * 32;
    const int n = blockIdx.z;
    const int tx = threadIdx.x & 31;
    const int ty = threadIdx.x >> 5;   // 0..7
    const float* __restrict__ src = cnn + (size_t)n * CDIM * HW;
    #pragma unroll
    for (int r = 0; r < 4; ++r) {
        int cc = ty + r * 8;
        int hw = hw0 + tx;
        if (hw < HW) tile[cc][tx] = src[(size_t)(c0 + cc) * HW + hw];
    }
    __syncthreads();
    #pragma unroll
    for (int r = 0; r < 4; ++r) {
        int hh = ty + r * 8;
        int hw = hw0 + hh;
        if (hw < HW) NH[(size_t)(n * HW + hw) * 512 + c0 + tx] = tile[tx][hh];
    }
}

// zero the 32 padded rows (512 cols) of both NH buffers
__global__ __launch_bounds__(256) void zero_pads(float* __restrict__ NHa,
                                                 float* __restrict__ NHb) {
    int t = blockIdx.x * 256 + threadIdx.x;
    if (t < 32 * 512) {
        NHa[(size_t)M_REAL * 512 + t] = 0.0f;
        NHb[(size_t)M_REAL * 512 + t] = 0.0f;
    }
}

// ---------------------------------------------------------------------------
// C[m][n] = relu( sum_k A[m][k] * W[n][k] + bias[n] )
// A row-major (lda), W row-major (ldw = K). Tiles 64x64xBK32, 4x4 per thread.
// M is padded (PADM) so no row guards needed.
// ---------------------------------------------------------------------------
#define BM 64
#define BN 64
#define BK 32
__global__ __launch_bounds__(256) void gemm_bias_relu(
    const float* __restrict__ A, int lda,
    const float* __restrict__ W, int ldw,
    const float* __restrict__ bias,
    float* __restrict__ Co, int ldc,
    int Kk) {
    __shared__ float As[BK][BM];
    __shared__ float Bs[BK][BN];
    const int m0 = blockIdx.x * BM;
    const int n0 = blockIdx.y * BN;
    const int tid = threadIdx.x;
    const int lr = tid >> 3;            // 0..31
    const int lk = (tid & 7) << 2;      // 0,4,...,28
    const int tx = tid & 15;            // 0..15 (cols)
    const int ty = tid >> 4;            // 0..15 (rows)

    float acc[4][4];
    #pragma unroll
    for (int a = 0; a < 4; ++a)
        #pragma unroll
        for (int b = 0; b < 4; ++b) acc[a][b] = 0.0f;

    for (int k0 = 0; k0 < Kk; k0 += BK) {
        #pragma unroll
        for (int h = 0; h < 2; ++h) {
            int row = lr + h * 32;
            float4 av = *(const float4*)&A[(size_t)(m0 + row) * lda + k0 + lk];
            As[lk + 0][row] = av.x; As[lk + 1][row] = av.y;
            As[lk + 2][row] = av.z; As[lk + 3][row] = av.w;
            float4 bv = *(const float4*)&W[(size_t)(n0 + row) * ldw + k0 + lk];
            Bs[lk + 0][row] = bv.x; Bs[lk + 1][row] = bv.y;
            Bs[lk + 2][row] = bv.z; Bs[lk + 3][row] = bv.w;
        }
        __syncthreads();
        #pragma unroll
        for (int k = 0; k < BK; ++k) {
            float4 a4 = *(const float4*)&As[k][ty * 4];
            float4 b4 = *(const float4*)&Bs[k][tx * 4];
            float av[4] = {a4.x, a4.y, a4.z, a4.w};
            float bv[4] = {b4.x, b4.y, b4.z, b4.w};
            #pragma unroll
            for (int ii = 0; ii < 4; ++ii)
                #pragma unroll
                for (int jj = 0; jj < 4; ++jj)
                    acc[ii][jj] = fmaf(av[ii], bv[jj], acc[ii][jj]);
        }
        __syncthreads();
    }

    float4 bb = *(const float4*)&bias[n0 + tx * 4];
    const float b0 = bb.x, b1 = bb.y, b2 = bb.z, b3 = bb.w;
    #pragma unroll
    for (int ii = 0; ii < 4; ++ii) {
        int row = m0 + ty * 4 + ii;
        float4 o;
        o.x = fmaxf(acc[ii][0] + b0, 0.0f);
        o.y = fmaxf(acc[ii][1] + b1, 0.0f);
        o.z = fmaxf(acc[ii][2] + b2, 0.0f);
        o.w = fmaxf(acc[ii][3] + b3, 0.0f);
        *(float4*)&Co[(size_t)row * ldc + n0 + tx * 4] = o;
    }
}

// ---------------------------------------------------------------------------
// message[q][c] = (1/64) * sum_k T[n*HW + idx[q][k]][c]  -> NH right half
// ---------------------------------------------------------------------------
__global__ __launch_bounds__(256) void gather_mean(const float* __restrict__ T,
                                                   const int* __restrict__ idx,
                                                   float* __restrict__ NH) {
    const int q = blockIdx.x;
    const int n = q / HW;
    const int t = threadIdx.x;
    __shared__ int nbr[KNN];
    if (t < KNN) nbr[t] = idx[(size_t)q * KNN + t];
    __syncthreads();
    float sum = 0.0f;
    #pragma unroll 8
    for (int k = 0; k < KNN; ++k) {
        int r = n * HW + nbr[k];
        sum += T[(size_t)r * CDIM + t];
    }
    NH[(size_t)q * 512 + CDIM + t] = sum * (1.0f / KNN);
}

// out[n][0:256][hw] = cnn_feature
__global__ __launch_bounds__(256) void copy_cnn(const float* __restrict__ cnn,
                                                float* __restrict__ out) {
    int f = blockIdx.x * 256 + threadIdx.x;
    const int per = CDIM * HW;
    if (f < NBATCH * per) {
        int n = f / per;
        int rem = f - n * per;
        out[(size_t)n * (2 * CDIM * HW) + rem] = cnn[f];
    }
}

// out[n][256 + c][hw] = Hf[(n*HW+hw)*512 + c]
__global__ __launch_bounds__(256) void final_out(const float* __restrict__ Hf,
                                                 float* __restrict__ out) {
    __shared__ float tile[32][33];
    const int hw0 = blockIdx.x * 32;
    const int c0 = blockIdx.y * 32;
    const int n = blockIdx.z;
    const int tx = threadIdx.x & 31;
    const int ty = threadIdx.x >> 5;
    #pragma unroll
    for (int r = 0; r < 4; ++r) {
        int hh = ty + r * 8;
        int hw = hw0 + hh;
        if (hw < HW) tile[hh][tx] = Hf[(size_t)(n * HW + hw) * 512 + c0 + tx];
    }
    __syncthreads();
    #pragma unroll
    for (int r = 0; r < 4; ++r) {
        int cc = ty + r * 8;
        int hw = hw0 + tx;
        if (hw < HW)
            out[(size_t)n * (2 * CDIM * HW) + (size_t)(CDIM + c0 + cc) * HW + hw] =
                tile[tx][cc];
    }
}

extern "C" void kernel_launch(void* const* d_in, const int* in_sizes, int n_in,
                              void* d_out, int out_size, void* d_ws, size_t ws_size,
                              hipStream_t stream) {
    const float* cnn   = (const float*)d_in[0];
    const float* pts   = (const float*)d_in[1];
    const float* mlp_w = (const float*)d_in[2];
    const float* mlp_b = (const float*)d_in[3];
    const float* rnn_w = (const float*)d_in[4];
    const float* rnn_b = (const float*)d_in[5];
    float* out = (float*)d_out;

    // workspace layout (fp32): NHa(7232x512) | NHb(7232x512) | T(7232x256) | idx(7200x64 int)
    float* NHa = (float*)d_ws;
    float* NHb = NHa + (size_t)PADM * 512;
    float* T   = NHb + (size_t)PADM * 512;
    int*   idx = (int*)(T + (size_t)PADM * CDIM);

    topk_kernel<<<M_REAL, 256, 0, stream>>>(pts, idx);
    init_h<<<dim3(113, 8, NBATCH), 256, 0, stream>>>(cnn, NHa);
    zero_pads<<<64, 256, 0, stream>>>(NHa, NHb);

    float* cur = NHa;
    float* nxt = NHb;
    for (int it = 0; it < 3; ++it) {
        // t = relu(mlp_w @ h + mlp_b): A = cur left half (lda=512), K=256
        gemm_bias_relu<<<dim3(PADM / BM, CDIM / BN), 256, 0, stream>>>(
            cur, 512, mlp_w, CDIM, mlp_b, T, CDIM, CDIM);
        // message = mean_k t[idx] -> cur right half
        gather_mean<<<M_REAL, 256, 0, stream>>>(T, idx, cur);
        // h' = relu(rnn_w @ [h;msg] + rnn_b): A = cur full row (K=512) -> nxt left half
        gemm_bias_relu<<<dim3(PADM / BM, CDIM / BN), 256, 0, stream>>>(
            cur, 512, rnn_w, 512, rnn_b, nxt, 512, 512);
        float* tmp = cur; cur = nxt; nxt = tmp;
    }

    copy_cnn<<<(NBATCH * CDIM * HW + 255) / 256, 256, 0, stream>>>(cnn, out);
    final_out<<<dim3(113, 8, NBATCH), 256, 0, stream>>>(cur, out);
}

// Round 3
// 250.058 us; speedup vs baseline: 2.7106x; 1.7216x over previous
//
#include <hip/hip_runtime.h>
#include <stdint.h>

typedef unsigned int uint;

#define HW 3600
#define NBATCH 2
#define CDIM 256
#define KNN 64
#define M_REAL 7200
#define PADM 7232          // 7200 padded to multiple of 64 (113*64)

using short8  = __attribute__((ext_vector_type(8))) short;
using floatx4 = __attribute__((ext_vector_type(4))) float;

__device__ inline unsigned short f2bf(float f) {   // RNE fp32 -> bf16 bits
    uint u = __float_as_uint(f);
    uint r = u + 0x7FFFu + ((u >> 16) & 1u);
    return (unsigned short)(r >> 16);
}
__device__ inline float bf2f(unsigned short b) {
    return __uint_as_float(((uint)b) << 16);
}

// ---------------------------------------------------------------------------
// Top-K: one WAVE (64-thread block) per query. d2 keys register-resident
// (57/lane). Two 8-bit radix passes on linearly-quantized 16-bit keys
// (spread bins -> minimal LDS atomic serialization), exact-key tie
// resolution. No cross-wave barriers.
// ---------------------------------------------------------------------------
__device__ inline void hist_select(uint* hist, uint* s_bin, uint* s_want,
                                   int lane, uint want) {
    uint h0 = hist[4 * lane + 0], h1 = hist[4 * lane + 1];
    uint h2 = hist[4 * lane + 2], h3 = hist[4 * lane + 3];
    hist[4 * lane + 0] = 0; hist[4 * lane + 1] = 0;
    hist[4 * lane + 2] = 0; hist[4 * lane + 3] = 0;
    uint c4 = h0 + h1 + h2 + h3;
    uint v = c4;
    #pragma unroll
    for (int off = 1; off < 64; off <<= 1) {
        uint o = __shfl_up(v, off, 64);
        if (lane >= off) v += o;
    }
    uint below = v - c4;                 // count in bins < 4*lane
    if (below < want && want <= v) {     // threshold bin is in my 4 bins
        uint b = 4 * lane, c = below;
        if (c + h0 < want) { c += h0; b = 4 * lane + 1;
            if (c + h1 < want) { c += h1; b = 4 * lane + 2;
                if (c + h2 < want) { c += h2; b = 4 * lane + 3; } } }
        *s_bin = b;
        *s_want = want - c;
    }
}

__global__ __launch_bounds__(64) void topk_kernel(const float* __restrict__ points,
                                                  int* __restrict__ idx_out) {
    const int q = blockIdx.x;
    const int n = q / HW;
    const int i = q - n * HW;
    const int lane = threadIdx.x;

    __shared__ uint hist[256];
    __shared__ uint s_bin, s_want, s_cnt;

    const float* __restrict__ px = points + (size_t)n * 3 * HW;
    const float* __restrict__ py = px + HW;
    const float* __restrict__ pz = py + HW;

    hist[4 * lane + 0] = 0; hist[4 * lane + 1] = 0;
    hist[4 * lane + 2] = 0; hist[4 * lane + 3] = 0;
    if (lane == 0) s_cnt = 0;

    const float xi = px[i], yi = py[i], zi = pz[i];
    const float sqi = xi * xi + yi * yi + zi * zi;

    float d2v[57];
    #pragma unroll
    for (int s = 0; s < 57; ++s) {
        int j = (s << 6) + lane;
        float d2 = 1e30f;
        if (j < HW) {
            float xj = px[j], yj = py[j], zj = pz[j];
            d2 = fmaxf(sqi + (xj * xj + yj * yj + zj * zj)
                       - 2.0f * (xi * xj + yi * yj + zi * zj), 0.0f);
        }
        d2v[s] = d2;
    }
    __syncthreads();

    // pass 1: high byte of q16 = min(d2*1024, 65535)  (linear -> spread bins)
    #pragma unroll
    for (int s = 0; s < 57; ++s) {
        uint q16 = (uint)fminf(d2v[s] * 1024.0f, 65535.0f);
        atomicAdd(&hist[q16 >> 8], 1u);
    }
    __syncthreads();
    hist_select(hist, &s_bin, &s_want, lane, KNN);
    __syncthreads();
    const uint qT8 = s_bin;
    const uint want2 = s_want;
    __syncthreads();

    // pass 2: low byte among survivors
    #pragma unroll
    for (int s = 0; s < 57; ++s) {
        uint q16 = (uint)fminf(d2v[s] * 1024.0f, 65535.0f);
        if ((q16 >> 8) == qT8) atomicAdd(&hist[q16 & 255u], 1u);
    }
    __syncthreads();
    hist_select(hist, &s_bin, &s_want, lane, want2);
    __syncthreads();
    const uint qT16 = (qT8 << 8) | s_bin;
    const uint want3 = s_want;

    // collect all strictly-below (exact subset of the true 64-NN set)
    #pragma unroll
    for (int s = 0; s < 57; ++s) {
        uint q16 = (uint)fminf(d2v[s] * 1024.0f, 65535.0f);
        if (q16 < qT16) {
            uint pos = atomicAdd(&s_cnt, 1u);
            idx_out[(size_t)q * KNN + pos] = (s << 6) + lane;
        }
    }
    // ties at qT16: exact (f32bits(d2), index) min, want3 rounds
    unsigned long long used = 0ULL;
    const int base = KNN - (int)want3;
    for (int r = 0; r < (int)want3; ++r) {
        unsigned long long best = ~0ULL;
        #pragma unroll
        for (int s = 0; s < 57; ++s) {
            uint q16 = (uint)fminf(d2v[s] * 1024.0f, 65535.0f);
            if (q16 == qT16 && !((used >> s) & 1ULL)) {
                unsigned long long key =
                    ((unsigned long long)__float_as_uint(d2v[s]) << 32)
                    | (uint)((s << 6) + lane);
                if (key < best) best = key;
            }
        }
        #pragma unroll
        for (int off = 1; off < 64; off <<= 1) {
            unsigned long long o = __shfl_xor(best, off, 64);
            if (o < best) best = o;
        }
        uint jw = (uint)best;
        if (lane == 0) idx_out[(size_t)q * KNN + base + r] = (int)jw;
        if ((int)(jw & 63u) == lane) used |= 1ULL << (jw >> 6);
    }
}

// ---------------------------------------------------------------------------
// fp32 -> bf16 bulk convert (weights)
// ---------------------------------------------------------------------------
__global__ __launch_bounds__(256) void f32_to_bf16(const float* __restrict__ in,
                                                   unsigned short* __restrict__ out,
                                                   int n) {
    int i = blockIdx.x * 256 + threadIdx.x;
    if (i < n) out[i] = f2bf(in[i]);
}

// ---------------------------------------------------------------------------
// h0 init: NH[(n*HW+hw)*512 + c] = bf16(cnn[n][c][hw])
// ---------------------------------------------------------------------------
__global__ __launch_bounds__(256) void init_h(const float* __restrict__ cnn,
                                              unsigned short* __restrict__ NH) {
    __shared__ float tile[32][33];
    const int hw0 = blockIdx.x * 32;
    const int c0 = blockIdx.y * 32;
    const int n = blockIdx.z;
    const int tx = threadIdx.x & 31;
    const int ty = threadIdx.x >> 5;   // 0..7
    const float* __restrict__ src = cnn + (size_t)n * CDIM * HW;
    #pragma unroll
    for (int r = 0; r < 4; ++r) {
        int cc = ty + r * 8;
        int hw = hw0 + tx;
        if (hw < HW) tile[cc][tx] = src[(size_t)(c0 + cc) * HW + hw];
    }
    __syncthreads();
    #pragma unroll
    for (int r = 0; r < 4; ++r) {
        int hh = ty + r * 8;
        int hw = hw0 + hh;
        if (hw < HW) NH[(size_t)(n * HW + hw) * 512 + c0 + tx] = f2bf(tile[tx][hh]);
    }
}

// zero the 32 padded rows (512 cols) of both NH buffers (bf16 0 == 0x0000)
__global__ __launch_bounds__(256) void zero_pads(unsigned short* __restrict__ NHa,
                                                 unsigned short* __restrict__ NHb) {
    int t = blockIdx.x * 256 + threadIdx.x;
    if (t < 32 * 512) {
        NHa[(size_t)M_REAL * 512 + t] = 0;
        NHb[(size_t)M_REAL * 512 + t] = 0;
    }
}

// ---------------------------------------------------------------------------
// bf16 MFMA GEMM: C[m][n] = relu( sum_k A[m][k]*W[n][k] + bias[n] )
// 64x64 tile, BK=64, 4 waves each computing a 32x32 quadrant (2x2 frags of
// 16x16x32). LDS rows padded to 72 bf16 (144 B = 36 banks -> 2-way, free).
// If Cf != nullptr the result is stored fp32 (final iteration), else bf16.
// ---------------------------------------------------------------------------
#define LDK 72
__global__ __launch_bounds__(256) void gemm_mfma(
    const unsigned short* __restrict__ A, int lda,
    const unsigned short* __restrict__ W, int ldw,
    const float* __restrict__ bias,
    unsigned short* __restrict__ Cb, float* __restrict__ Cf,
    int ldc, int Kk) {
    __shared__ __align__(16) unsigned short As[64 * LDK];
    __shared__ __align__(16) unsigned short Bs[64 * LDK];
    const int m0 = blockIdx.x * 64;
    const int n0 = blockIdx.y * 64;
    const int tid = threadIdx.x;
    const int lane = tid & 63;
    const int w = tid >> 6;
    const int wm = (w & 1) * 32;
    const int wn = (w >> 1) * 32;
    const int l15 = lane & 15;
    const int qd = lane >> 4;            // quad 0..3

    floatx4 acc[2][2];
    #pragma unroll
    for (int a = 0; a < 2; ++a)
        #pragma unroll
        for (int b = 0; b < 2; ++b)
            acc[a][b] = (floatx4){0.f, 0.f, 0.f, 0.f};

    const int sr = tid >> 2;             // staging row 0..63
    const int sc = (tid & 3) * 16;       // staging col base (bf16 elems)

    for (int k0 = 0; k0 < Kk; k0 += 64) {
        const unsigned short* ga = &A[(size_t)(m0 + sr) * lda + k0 + sc];
        const unsigned short* gb = &W[(size_t)(n0 + sr) * ldw + k0 + sc];
        float4 av0 = *(const float4*)(ga);
        float4 av1 = *(const float4*)(ga + 8);
        float4 bv0 = *(const float4*)(gb);
        float4 bv1 = *(const float4*)(gb + 8);
        *(float4*)&As[sr * LDK + sc] = av0;
        *(float4*)&As[sr * LDK + sc + 8] = av1;
        *(float4*)&Bs[sr * LDK + sc] = bv0;
        *(float4*)&Bs[sr * LDK + sc + 8] = bv1;
        __syncthreads();
        #pragma unroll
        for (int ks = 0; ks < 64; ks += 32) {
            short8 a0 = *(const short8*)&As[(wm + l15) * LDK + ks + qd * 8];
            short8 a1 = *(const short8*)&As[(wm + 16 + l15) * LDK + ks + qd * 8];
            short8 b0 = *(const short8*)&Bs[(wn + l15) * LDK + ks + qd * 8];
            short8 b1 = *(const short8*)&Bs[(wn + 16 + l15) * LDK + ks + qd * 8];
            acc[0][0] = __builtin_amdgcn_mfma_f32_16x16x32_bf16(a0, b0, acc[0][0], 0, 0, 0);
            acc[0][1] = __builtin_amdgcn_mfma_f32_16x16x32_bf16(a0, b1, acc[0][1], 0, 0, 0);
            acc[1][0] = __builtin_amdgcn_mfma_f32_16x16x32_bf16(a1, b0, acc[1][0], 0, 0, 0);
            acc[1][1] = __builtin_amdgcn_mfma_f32_16x16x32_bf16(a1, b1, acc[1][1], 0, 0, 0);
        }
        __syncthreads();
    }

    #pragma unroll
    for (int in = 0; in < 2; ++in) {
        int col = n0 + wn + in * 16 + l15;
        float bv = bias[col];
        #pragma unroll
        for (int im = 0; im < 2; ++im) {
            #pragma unroll
            for (int r = 0; r < 4; ++r) {
                int row = m0 + wm + im * 16 + qd * 4 + r;
                float v = fmaxf(acc[im][in][r] + bv, 0.0f);
                if (Cf) Cf[(size_t)row * ldc + col] = v;
                else    Cb[(size_t)row * ldc + col] = f2bf(v);
            }
        }
    }
}

// ---------------------------------------------------------------------------
// message[q][c] = (1/64) * sum_k T[n*HW+idx[q][k]][c]  -> NH right half (bf16)
// block=128, each thread handles a column PAIR via 4-byte loads.
// ---------------------------------------------------------------------------
__global__ __launch_bounds__(128) void gather_mean(const unsigned short* __restrict__ T,
                                                   const int* __restrict__ idx,
                                                   unsigned short* __restrict__ NH) {
    const int q = blockIdx.x;
    const int n = q / HW;
    const int t = threadIdx.x;          // 0..127 -> cols 2t, 2t+1
    __shared__ int nbr[KNN];
    if (t < KNN) nbr[t] = idx[(size_t)q * KNN + t];
    __syncthreads();
    float s0 = 0.0f, s1 = 0.0f;
    #pragma unroll 8
    for (int k = 0; k < KNN; ++k) {
        int r = n * HW + nbr[k];
        uint v = *(const uint*)&T[(size_t)r * CDIM + 2 * t];
        s0 += bf2f((unsigned short)(v & 0xFFFFu));
        s1 += bf2f((unsigned short)(v >> 16));
    }
    uint o = (uint)f2bf(s0 * (1.0f / KNN)) | ((uint)f2bf(s1 * (1.0f / KNN)) << 16);
    *(uint*)&NH[(size_t)q * 512 + CDIM + 2 * t] = o;
}

// out[n][0:256][hw] = cnn_feature (fp32 passthrough)
__global__ __launch_bounds__(256) void copy_cnn(const float* __restrict__ cnn,
                                                float* __restrict__ out) {
    int f = blockIdx.x * 256 + threadIdx.x;
    const int per = CDIM * HW;
    if (f < NBATCH * per) {
        int n = f / per;
        int rem = f - n * per;
        out[(size_t)n * (2 * CDIM * HW) + rem] = cnn[f];
    }
}

// out[n][256 + c][hw] = Hf32[(n*HW+hw)*256 + c]
__global__ __launch_bounds__(256) void final_out(const float* __restrict__ Hf,
                                                 float* __restrict__ out) {
    __shared__ float tile[32][33];
    const int hw0 = blockIdx.x * 32;
    const int c0 = blockIdx.y * 32;
    const int n = blockIdx.z;
    const int tx = threadIdx.x & 31;
    const int ty = threadIdx.x >> 5;
    #pragma unroll
    for (int r = 0; r < 4; ++r) {
        int hh = ty + r * 8;
        int hw = hw0 + hh;
        if (hw < HW) tile[hh][tx] = Hf[(size_t)(n * HW + hw) * CDIM + c0 + tx];
    }
    __syncthreads();
    #pragma unroll
    for (int r = 0; r < 4; ++r) {
        int cc = ty + r * 8;
        int hw = hw0 + tx;
        if (hw < HW)
            out[(size_t)n * (2 * CDIM * HW) + (size_t)(CDIM + c0 + cc) * HW + hw] =
                tile[tx][cc];
    }
}

extern "C" void kernel_launch(void* const* d_in, const int* in_sizes, int n_in,
                              void* d_out, int out_size, void* d_ws, size_t ws_size,
                              hipStream_t stream) {
    const float* cnn   = (const float*)d_in[0];
    const float* pts   = (const float*)d_in[1];
    const float* mlp_w = (const float*)d_in[2];
    const float* mlp_b = (const float*)d_in[3];
    const float* rnn_w = (const float*)d_in[4];
    const float* rnn_b = (const float*)d_in[5];
    float* out = (float*)d_out;

    // workspace (bf16 pipeline):
    // NHa(7232x512 u16) | NHb(7232x512 u16, reused as fp32 7232x256 at the end)
    // | Tb(7232x256 u16) | mlpw_b(65536 u16) | rnnw_b(131072 u16) | idx(7200x64 int)
    unsigned short* NHa    = (unsigned short*)d_ws;
    unsigned short* NHb    = NHa + (size_t)PADM * 512;
    unsigned short* Tb     = NHb + (size_t)PADM * 512;
    unsigned short* mlpw_b = Tb + (size_t)PADM * CDIM;
    unsigned short* rnnw_b = mlpw_b + 65536;
    int*            idx    = (int*)(rnnw_b + 131072);

    f32_to_bf16<<<256, 256, 0, stream>>>(mlp_w, mlpw_b, 65536);
    f32_to_bf16<<<512, 256, 0, stream>>>(rnn_w, rnnw_b, 131072);
    topk_kernel<<<M_REAL, 64, 0, stream>>>(pts, idx);
    init_h<<<dim3(113, 8, NBATCH), 256, 0, stream>>>(cnn, NHa);
    zero_pads<<<64, 256, 0, stream>>>(NHa, NHb);

    unsigned short* cur = NHa;
    unsigned short* nxt = NHb;
    for (int it = 0; it < 3; ++it) {
        // t = relu(mlp_w @ h + mlp_b): A = cur left half, K=256 -> Tb (bf16)
        gemm_mfma<<<dim3(PADM / 64, CDIM / 64), 256, 0, stream>>>(
            cur, 512, mlpw_b, CDIM, mlp_b, Tb, nullptr, CDIM, CDIM);
        // message = mean_k t[idx] -> cur right half
        gather_mean<<<M_REAL, 128, 0, stream>>>(Tb, idx, cur);
        // h' = relu(rnn_w @ [h;msg] + rnn_b), K=512
        if (it < 2)
            gemm_mfma<<<dim3(PADM / 64, CDIM / 64), 256, 0, stream>>>(
                cur, 512, rnnw_b, 512, rnn_b, nxt, nullptr, 512, 512);
        else  // final: fp32 output into the (now free) nxt buffer
            gemm_mfma<<<dim3(PADM / 64, CDIM / 64), 256, 0, stream>>>(
                cur, 512, rnnw_b, 512, rnn_b, nullptr, (float*)nxt, CDIM, 512);
        unsigned short* tmp = cur; cur = nxt; nxt = tmp;
    }

    copy_cnn<<<(NBATCH * CDIM * HW + 255) / 256, 256, 0, stream>>>(cnn, out);
    final_out<<<dim3(113, 8, NBATCH), 256, 0, stream>>>((const float*)cur, out);
}

// Round 5
// 234.977 us; speedup vs baseline: 2.8846x; 1.0642x over previous
//
#include <hip/hip_runtime.h>
#include <stdint.h>

typedef unsigned int uint;

#define HW 3600
#define NBATCH 2
#define CDIM 256
#define KNN 64
#define M_REAL 7200
#define PADM 7232          // 7200 padded to multiple of 64 (113*64)
#define QPB 8              // topk queries per block (one per wave)

using short8  = __attribute__((ext_vector_type(8))) short;
using floatx4 = __attribute__((ext_vector_type(4))) float;

__device__ inline unsigned short f2bf(float f) {   // RNE fp32 -> bf16 bits
    uint u = __float_as_uint(f);
    uint r = u + 0x7FFFu + ((u >> 16) & 1u);
    return (unsigned short)(r >> 16);
}
__device__ inline float bf2f(unsigned short b) {
    return __uint_as_float(((uint)b) << 16);
}

// ---------------------------------------------------------------------------
// Top-K: 512-thread blocks, 8 queries/block (one per wave). Candidate points
// staged once into LDS (planar x/y/z, stride-1 b32 reads = conflict-free).
// Per-wave private 256-bin histograms; explicit __syncthreads() between
// phases (all phases are block-uniform) — the barrier-free wave-sync variant
// faulted in round 4.
// Two 8-bit radix passes on linearly-quantized 16-bit keys, exact-key ties.
// ---------------------------------------------------------------------------
__device__ inline void wave_select(uint* hist, uint* s_bin, uint* s_want,
                                   int lane, uint want) {
    uint h0 = hist[4 * lane + 0], h1 = hist[4 * lane + 1];
    uint h2 = hist[4 * lane + 2], h3 = hist[4 * lane + 3];
    hist[4 * lane + 0] = 0; hist[4 * lane + 1] = 0;
    hist[4 * lane + 2] = 0; hist[4 * lane + 3] = 0;
    uint c4 = h0 + h1 + h2 + h3;
    uint v = c4;
    #pragma unroll
    for (int off = 1; off < 64; off <<= 1) {
        uint o = __shfl_up(v, off, 64);
        if (lane >= off) v += o;
    }
    uint below = v - c4;                 // count in bins < 4*lane
    if (below < want && want <= v) {     // threshold bin is in my 4 bins
        uint b = 4 * lane, c = below;
        if (c + h0 < want) { c += h0; b = 4 * lane + 1;
            if (c + h1 < want) { c += h1; b = 4 * lane + 2;
                if (c + h2 < want) { c += h2; b = 4 * lane + 3; } } }
        *s_bin = b;
        *s_want = want - c;
    }
}

__global__ __launch_bounds__(512) void topk_kernel(const float* __restrict__ points,
                                                   int* __restrict__ idx_out) {
    const int wv = threadIdx.x >> 6;
    const int lane = threadIdx.x & 63;
    const int q = blockIdx.x * QPB + wv;
    const int n = (blockIdx.x * QPB) / HW;     // batch uniform per block (450 | 8)
    const int i = q - n * HW;

    __shared__ float sx[HW], sy[HW], sz[HW];   // 43200 B
    __shared__ uint hist[QPB][256];            // 8192 B
    __shared__ uint s_bin[QPB], s_want[QPB], s_cnt[QPB];

    const float* __restrict__ px = points + (size_t)n * 3 * HW;
    const float* __restrict__ py = px + HW;
    const float* __restrict__ pz = py + HW;

    for (int j = threadIdx.x; j < HW; j += 512) {
        sx[j] = px[j]; sy[j] = py[j]; sz[j] = pz[j];
    }
    hist[wv][4 * lane + 0] = 0; hist[wv][4 * lane + 1] = 0;
    hist[wv][4 * lane + 2] = 0; hist[wv][4 * lane + 3] = 0;
    if (lane == 0) s_cnt[wv] = 0;
    __syncthreads();

    const float xi = sx[i], yi = sy[i], zi = sz[i];
    const float sqi = xi * xi + yi * yi + zi * zi;

    // distances + quantize once; pack q16 pairs (29 VGPRs)
    uint qp[29];
    #pragma unroll
    for (int s = 0; s < 57; ++s) {
        int j = (s << 6) + lane;
        uint q16 = 0xFFFFu;                     // OOB sentinel
        if (j < HW) {
            float xj = sx[j], yj = sy[j], zj = sz[j];
            float d2 = fmaxf(sqi + (xj * xj + yj * yj + zj * zj)
                             - 2.0f * (xi * xj + yi * yj + zi * zj), 0.0f);
            q16 = (uint)fminf(d2 * 1024.0f, 65535.0f);
        }
        if (s & 1) qp[s >> 1] |= q16 << 16; else qp[s >> 1] = q16;
    }
    #define Q16(s) ((qp[(s) >> 1] >> (((s) & 1) << 4)) & 0xFFFFu)

    // pass 1: high byte (wave-private histogram)
    #pragma unroll
    for (int s = 0; s < 57; ++s) atomicAdd(&hist[wv][Q16(s) >> 8], 1u);
    __syncthreads();
    wave_select(&hist[wv][0], &s_bin[wv], &s_want[wv], lane, KNN);
    __syncthreads();
    const uint qT8 = s_bin[wv];
    const uint want2 = s_want[wv];
    __syncthreads();

    // pass 2: low byte among survivors
    #pragma unroll
    for (int s = 0; s < 57; ++s) {
        uint k = Q16(s);
        if ((k >> 8) == qT8) atomicAdd(&hist[wv][k & 255u], 1u);
    }
    __syncthreads();
    wave_select(&hist[wv][0], &s_bin[wv], &s_want[wv], lane, want2);
    __syncthreads();
    const uint qT16 = (qT8 << 8) | s_bin[wv];
    const uint want3 = s_want[wv];

    // collect all strictly-below (exact subset of the true 64-NN set)
    #pragma unroll
    for (int s = 0; s < 57; ++s) {
        if (Q16(s) < qT16) {
            uint pos = atomicAdd(&s_cnt[wv], 1u);
            if (pos < KNN) idx_out[(size_t)q * KNN + pos] = (s << 6) + lane;
        }
    }
    // ties at qT16: exact (f32bits(d2), index) min, want3 rounds.
    // Per-wave divergent trip counts -> shuffle-only, no barriers below.
    unsigned long long used = 0ULL;
    const int base = KNN - (int)want3;
    for (int r = 0; r < (int)want3; ++r) {
        unsigned long long best = ~0ULL;
        #pragma unroll
        for (int s = 0; s < 57; ++s) {
            int j = (s << 6) + lane;
            if (j < HW && Q16(s) == qT16 && !((used >> s) & 1ULL)) {
                float xj = sx[j], yj = sy[j], zj = sz[j];
                float d2 = fmaxf(sqi + (xj * xj + yj * yj + zj * zj)
                                 - 2.0f * (xi * xj + yi * yj + zi * zj), 0.0f);
                unsigned long long key =
                    ((unsigned long long)__float_as_uint(d2) << 32) | (uint)j;
                if (key < best) best = key;
            }
        }
        #pragma unroll
        for (int off = 1; off < 64; off <<= 1) {
            unsigned long long o = __shfl_xor(best, off, 64);
            if (o < best) best = o;
        }
        uint jw = (uint)best;
        if (lane == 0) idx_out[(size_t)q * KNN + base + r] = (int)jw;
        if ((int)(jw & 63u) == lane) used |= 1ULL << (jw >> 6);
    }
    #undef Q16
}

// ---------------------------------------------------------------------------
// setup fusion: weight bf16 converts + NH pad-row zeroing, one launch
// ---------------------------------------------------------------------------
__global__ __launch_bounds__(256) void setup_kernel(
    const float* __restrict__ mw, const float* __restrict__ rw,
    unsigned short* __restrict__ mo, unsigned short* __restrict__ ro,
    unsigned short* __restrict__ NHa, unsigned short* __restrict__ NHb) {
    int i = blockIdx.x * 256 + threadIdx.x;       // grid covers 131072
    if (i < 65536) mo[i] = f2bf(mw[i]);
    ro[i] = f2bf(rw[i]);
    if (i < 32 * 512) {
        NHa[(size_t)M_REAL * 512 + i] = 0;
        NHb[(size_t)M_REAL * 512 + i] = 0;
    }
}

// ---------------------------------------------------------------------------
// h0 init + passthrough: NH[(n*HW+hw)*512+c] = bf16(cnn[n][c][hw]);
// out[n][c][hw] = cnn[n][c][hw]  (cnn read once)
// ---------------------------------------------------------------------------
__global__ __launch_bounds__(256) void init_h(const float* __restrict__ cnn,
                                              unsigned short* __restrict__ NH,
                                              float* __restrict__ out) {
    __shared__ float tile[32][33];
    const int hw0 = blockIdx.x * 32;
    const int c0 = blockIdx.y * 32;
    const int n = blockIdx.z;
    const int tx = threadIdx.x & 31;
    const int ty = threadIdx.x >> 5;   // 0..7
    const float* __restrict__ src = cnn + (size_t)n * CDIM * HW;
    #pragma unroll
    for (int r = 0; r < 4; ++r) {
        int cc = ty + r * 8;
        int hw = hw0 + tx;
        if (hw < HW) {
            float v = src[(size_t)(c0 + cc) * HW + hw];
            tile[cc][tx] = v;
            out[(size_t)n * (2 * CDIM * HW) + (size_t)(c0 + cc) * HW + hw] = v;
        }
    }
    __syncthreads();
    #pragma unroll
    for (int r = 0; r < 4; ++r) {
        int hh = ty + r * 8;
        int hw = hw0 + hh;
        if (hw < HW) NH[(size_t)(n * HW + hw) * 512 + c0 + tx] = f2bf(tile[tx][hh]);
    }
}

// ---------------------------------------------------------------------------
// bf16 MFMA GEMM: C[m][n] = relu( sum_k A[m][k]*W[n][k] + bias[n] )
// 64x64 tile, BK=64, 4 waves each computing a 32x32 quadrant (2x2 frags of
// 16x16x32). LDS rows padded to 72 bf16 (144 B -> 2-way aliasing, free).
// If Cf != nullptr the result is stored fp32 (final iteration), else bf16.
// ---------------------------------------------------------------------------
#define LDK 72
__global__ __launch_bounds__(256) void gemm_mfma(
    const unsigned short* __restrict__ A, int lda,
    const unsigned short* __restrict__ W, int ldw,
    const float* __restrict__ bias,
    unsigned short* __restrict__ Cb, float* __restrict__ Cf,
    int ldc, int Kk) {
    __shared__ __align__(16) unsigned short As[64 * LDK];
    __shared__ __align__(16) unsigned short Bs[64 * LDK];
    const int m0 = blockIdx.x * 64;
    const int n0 = blockIdx.y * 64;
    const int tid = threadIdx.x;
    const int lane = tid & 63;
    const int w = tid >> 6;
    const int wm = (w & 1) * 32;
    const int wn = (w >> 1) * 32;
    const int l15 = lane & 15;
    const int qd = lane >> 4;            // quad 0..3

    floatx4 acc[2][2];
    #pragma unroll
    for (int a = 0; a < 2; ++a)
        #pragma unroll
        for (int b = 0; b < 2; ++b)
            acc[a][b] = (floatx4){0.f, 0.f, 0.f, 0.f};

    const int sr = tid >> 2;             // staging row 0..63
    const int sc = (tid & 3) * 16;       // staging col base (bf16 elems)

    for (int k0 = 0; k0 < Kk; k0 += 64) {
        const unsigned short* ga = &A[(size_t)(m0 + sr) * lda + k0 + sc];
        const unsigned short* gb = &W[(size_t)(n0 + sr) * ldw + k0 + sc];
        float4 av0 = *(const float4*)(ga);
        float4 av1 = *(const float4*)(ga + 8);
        float4 bv0 = *(const float4*)(gb);
        float4 bv1 = *(const float4*)(gb + 8);
        *(float4*)&As[sr * LDK + sc] = av0;
        *(float4*)&As[sr * LDK + sc + 8] = av1;
        *(float4*)&Bs[sr * LDK + sc] = bv0;
        *(float4*)&Bs[sr * LDK + sc + 8] = bv1;
        __syncthreads();
        #pragma unroll
        for (int ks = 0; ks < 64; ks += 32) {
            short8 a0 = *(const short8*)&As[(wm + l15) * LDK + ks + qd * 8];
            short8 a1 = *(const short8*)&As[(wm + 16 + l15) * LDK + ks + qd * 8];
            short8 b0 = *(const short8*)&Bs[(wn + l15) * LDK + ks + qd * 8];
            short8 b1 = *(const short8*)&Bs[(wn + 16 + l15) * LDK + ks + qd * 8];
            acc[0][0] = __builtin_amdgcn_mfma_f32_16x16x32_bf16(a0, b0, acc[0][0], 0, 0, 0);
            acc[0][1] = __builtin_amdgcn_mfma_f32_16x16x32_bf16(a0, b1, acc[0][1], 0, 0, 0);
            acc[1][0] = __builtin_amdgcn_mfma_f32_16x16x32_bf16(a1, b0, acc[1][0], 0, 0, 0);
            acc[1][1] = __builtin_amdgcn_mfma_f32_16x16x32_bf16(a1, b1, acc[1][1], 0, 0, 0);
        }
        __syncthreads();
    }

    #pragma unroll
    for (int in = 0; in < 2; ++in) {
        int col = n0 + wn + in * 16 + l15;
        float bv = bias[col];
        #pragma unroll
        for (int im = 0; im < 2; ++im) {
            #pragma unroll
            for (int r = 0; r < 4; ++r) {
                int row = m0 + wm + im * 16 + qd * 4 + r;
                float v = fmaxf(acc[im][in][r] + bv, 0.0f);
                if (Cf) Cf[(size_t)row * ldc + col] = v;
                else    Cb[(size_t)row * ldc + col] = f2bf(v);
            }
        }
    }
}

// ---------------------------------------------------------------------------
// message[q][c] = (1/64)*sum_k T[n*HW+idx[q][k]][c] -> NH right half (bf16)
// wave per query: 32 lanes x 8 cols (uint4 = 16B loads), k parity by
// lane-half, shfl_xor(32) cross-half reduce. Gathered index clamped to
// [0,HW-1]: any idx corruption shows as absmax error, not a fault.
// ---------------------------------------------------------------------------
__global__ __launch_bounds__(256) void gather_mean(const unsigned short* __restrict__ T,
                                                   const int* __restrict__ idx,
                                                   unsigned short* __restrict__ NH) {
    const int q = blockIdx.x * 4 + (threadIdx.x >> 6);
    const int lane = threadIdx.x & 63;
    const int n = q / HW;
    const int half = lane >> 5;           // k parity
    const int c8 = (lane & 31) * 8;       // 8-col strip

    const int nbrL = idx[(size_t)q * KNN + lane];
    float acc[8] = {0, 0, 0, 0, 0, 0, 0, 0};
    #pragma unroll 4
    for (int it = 0; it < 32; ++it) {
        int k = 2 * it + half;
        int j = __shfl(nbrL, k, 64);
        j = min(max(j, 0), HW - 1);       // defensive clamp
        int r = n * HW + j;
        uint4 v = *(const uint4*)&T[(size_t)r * CDIM + c8];
        acc[0] += bf2f((unsigned short)(v.x & 0xFFFFu));
        acc[1] += bf2f((unsigned short)(v.x >> 16));
        acc[2] += bf2f((unsigned short)(v.y & 0xFFFFu));
        acc[3] += bf2f((unsigned short)(v.y >> 16));
        acc[4] += bf2f((unsigned short)(v.z & 0xFFFFu));
        acc[5] += bf2f((unsigned short)(v.z >> 16));
        acc[6] += bf2f((unsigned short)(v.w & 0xFFFFu));
        acc[7] += bf2f((unsigned short)(v.w >> 16));
    }
    #pragma unroll
    for (int c = 0; c < 8; ++c) acc[c] += __shfl_xor(acc[c], 32, 64);
    if (half == 0) {
        uint4 o;
        o.x = (uint)f2bf(acc[0] * (1.0f / KNN)) | ((uint)f2bf(acc[1] * (1.0f / KNN)) << 16);
        o.y = (uint)f2bf(acc[2] * (1.0f / KNN)) | ((uint)f2bf(acc[3] * (1.0f / KNN)) << 16);
        o.z = (uint)f2bf(acc[4] * (1.0f / KNN)) | ((uint)f2bf(acc[5] * (1.0f / KNN)) << 16);
        o.w = (uint)f2bf(acc[6] * (1.0f / KNN)) | ((uint)f2bf(acc[7] * (1.0f / KNN)) << 16);
        *(uint4*)&NH[(size_t)q * 512 + CDIM + c8] = o;
    }
}

// out[n][256 + c][hw] = Hf32[(n*HW+hw)*256 + c]
__global__ __launch_bounds__(256) void final_out(const float* __restrict__ Hf,
                                                 float* __restrict__ out) {
    __shared__ float tile[32][33];
    const int hw0 = blockIdx.x * 32;
    const int c0 = blockIdx.y * 32;
    const int n = blockIdx.z;
    const int tx = threadIdx.x & 31;
    const int ty = threadIdx.x >> 5;
    #pragma unroll
    for (int r = 0; r < 4; ++r) {
        int hh = ty + r * 8;
        int hw = hw0 + hh;
        if (hw < HW) tile[hh][tx] = Hf[(size_t)(n * HW + hw) * CDIM + c0 + tx];
    }
    __syncthreads();
    #pragma unroll
    for (int r = 0; r < 4; ++r) {
        int cc = ty + r * 8;
        int hw = hw0 + tx;
        if (hw < HW)
            out[(size_t)n * (2 * CDIM * HW) + (size_t)(CDIM + c0 + cc) * HW + hw] =
                tile[tx][cc];
    }
}

extern "C" void kernel_launch(void* const* d_in, const int* in_sizes, int n_in,
                              void* d_out, int out_size, void* d_ws, size_t ws_size,
                              hipStream_t stream) {
    const float* cnn   = (const float*)d_in[0];
    const float* pts   = (const float*)d_in[1];
    const float* mlp_w = (const float*)d_in[2];
    const float* mlp_b = (const float*)d_in[3];
    const float* rnn_w = (const float*)d_in[4];
    const float* rnn_b = (const float*)d_in[5];
    float* out = (float*)d_out;

    // workspace (bf16 pipeline):
    // NHa(7232x512 u16) | NHb(7232x512 u16, reused as fp32 7232x256 at the end)
    // | Tb(7232x256 u16) | mlpw_b(65536 u16) | rnnw_b(131072 u16) | idx(7200x64 int)
    unsigned short* NHa    = (unsigned short*)d_ws;
    unsigned short* NHb    = NHa + (size_t)PADM * 512;
    unsigned short* Tb     = NHb + (size_t)PADM * 512;
    unsigned short* mlpw_b = Tb + (size_t)PADM * CDIM;
    unsigned short* rnnw_b = mlpw_b + 65536;
    int*            idx    = (int*)(rnnw_b + 131072);

    setup_kernel<<<512, 256, 0, stream>>>(mlp_w, rnn_w, mlpw_b, rnnw_b, NHa, NHb);
    topk_kernel<<<M_REAL / QPB, 512, 0, stream>>>(pts, idx);
    init_h<<<dim3(113, 8, NBATCH), 256, 0, stream>>>(cnn, NHa, out);

    unsigned short* cur = NHa;
    unsigned short* nxt = NHb;
    for (int it = 0; it < 3; ++it) {
        // t = relu(mlp_w @ h + mlp_b): A = cur left half, K=256 -> Tb (bf16)
        gemm_mfma<<<dim3(PADM / 64, CDIM / 64), 256, 0, stream>>>(
            cur, 512, mlpw_b, CDIM, mlp_b, Tb, nullptr, CDIM, CDIM);
        // message = mean_k t[idx] -> cur right half
        gather_mean<<<M_REAL / 4, 256, 0, stream>>>(Tb, idx, cur);
        // h' = relu(rnn_w @ [h;msg] + rnn_b), K=512
        if (it < 2)
            gemm_mfma<<<dim3(PADM / 64, CDIM / 64), 256, 0, stream>>>(
                cur, 512, rnnw_b, 512, rnn_b, nxt, nullptr, 512, 512);
        else  // final: fp32 output into the (now free) nxt buffer
            gemm_mfma<<<dim3(PADM / 64, CDIM / 64), 256, 0, stream>>>(
                cur, 512, rnnw_b, 512, rnn_b, nullptr, (float*)nxt, CDIM, 512);
        unsigned short* tmp = cur; cur = nxt; nxt = tmp;
    }

    final_out<<<dim3(113, 8, NBATCH), 256, 0, stream>>>((const float*)cur, out);
}